// Round 6
// baseline (309.559 us; speedup 1.0000x reference)
//
#include <hip/hip_runtime.h>

// cAttention B=8, C=16, L=512, D=256 (fp32 in/out).
// R11 = R10 (83us: stage2 fused into score phase) + score VALU diet:
//   - Es stores HALF-exponent e^z (exp2(clamp(z*log2e, +-7.5)) -- same
//     effective clamp as R6's +-15 on 2z); p = Eq*Ek <= 2^15 fits f16.
//   - 4-way BATCHED RECIPROCAL: sum w_i/A_i = num/(A0A1A2A3), one
//     v_rcp_f32 per 4 elements instead of 4 (rcp was ~45% of score issue).
//     A = 1+p^2 <= 2^30, D <= 2^120 < f32 max: safe.
//   - bsc precompute: (bqkv + [bh,0])*log2e folded into one epilogue fma.
//   - s_setprio(1) around the fused-phase MFMA quad (barrier-free phase =>
//     wave diversity; T5-positive regime).
//   Stage1 / staging / epilogues structurally unchanged from R10.

typedef __attribute__((ext_vector_type(8))) short bf16x8;
typedef __attribute__((ext_vector_type(4))) float f32x4;
typedef __attribute__((ext_vector_type(8))) _Float16 h16x8;
typedef __attribute__((ext_vector_type(4))) _Float16 h16x4;
typedef const __attribute__((address_space(1))) void* gp1_t;
typedef __attribute__((address_space(3))) void* lp3_t;

__device__ __forceinline__ unsigned short f2bf(float f) {
  union { float f; unsigned int u; } v; v.f = f;
  return (unsigned short)((v.u + 0x7FFFu + ((v.u >> 16) & 1u)) >> 16);
}

__device__ __forceinline__ unsigned int cvt_pk_bf16(float a, float b) {
  unsigned int r;
  asm("v_cvt_pk_bf16_f32 %0, %1, %2" : "=v"(r) : "v"(a), "v"(b));
  return r;  // lo = bf16(a), hi = bf16(b)
}

// ---- prep: Wqb_t = transpose-pack(Wqkv[0:512]) ; Wcb_t = pack(Wout @ Wv) ;
//      bcomb = Wout @ bv ; bsc = (bqkv[0:512] + [bh,0])*log2e.
//      W layout: W_t[k>>3][n][8] (8 consecutive k per 16B). ----
__global__ __launch_bounds__(256) void ca_prep_kernel(
    const float* __restrict__ Wqkv, const float* __restrict__ Wout,
    const float* __restrict__ bqkv, const float* __restrict__ bh,
    unsigned short* __restrict__ Wqb_t, unsigned short* __restrict__ Wcb_t,
    float* __restrict__ bcomb, float* __restrict__ bsc) {
  const int blk = blockIdx.x;
  if (blk < 64) {
    // convert+transpose Wqkv (512x256 f32) -> Wqb_t[k8][512][8] bf16
    const int t = blk * 256 + threadIdx.x;  // 16384 threads
    const int k8 = t >> 9, n = t & 511;
    const float* src = Wqkv + (size_t)n * 256 + k8 * 8;
    const float4 v0 = *(const float4*)src;
    const float4 v1 = *(const float4*)(src + 4);
    bf16x8 o;
    o[0] = (short)f2bf(v0.x); o[1] = (short)f2bf(v0.y);
    o[2] = (short)f2bf(v0.z); o[3] = (short)f2bf(v0.w);
    o[4] = (short)f2bf(v1.x); o[5] = (short)f2bf(v1.y);
    o[6] = (short)f2bf(v1.z); o[7] = (short)f2bf(v1.w);
    *(bf16x8*)(Wqb_t + (size_t)t * 8) = o;  // t = k8*512 + n: coalesced store
    return;
  }
  const int dp = blk - 64;       // output row n (0..255)
  const int e = threadIdx.x;     // k (0..255)
  if (dp < 2) {                  // bsc[512]: scaled combined bias
    const int n = dp * 256 + e;
    const float b = bqkv[n] + (n < 256 ? bh[n] : 0.f);
    bsc[n] = b * 1.4426950408889634f;  // log2(e)
  }
  const float* wrow = Wout + (size_t)dp * 256;
  float acc = 0.f;
#pragma unroll 8
  for (int f = 0; f < 256; ++f)
    acc = fmaf(wrow[f], Wqkv[(size_t)(512 + f) * 256 + e], acc);
  Wcb_t[((size_t)(e >> 3) * 256 + dp) * 8 + (e & 7)] = f2bf(acc);
  if (e == 0) {
    float b = 0.f;
    for (int f = 0; f < 256; ++f) b = fmaf(wrow[f], bqkv[512 + f], b);
    bcomb[dp] = b;
  }
}

// ---- fused: qk MFMA + exp + (score || out MFMA) + softmax diag ----
__global__ __launch_bounds__(512, 6) void ca_fused(
    const float* __restrict__ x,               // (8,16,512,256) fp32
    const unsigned short* __restrict__ Wqb_t,  // [32][512][8] bf16
    const unsigned short* __restrict__ Wcb_t,  // [32][256][8] bf16
    const float* __restrict__ bsc,             // 512: (bias)*log2e
    const float* __restrict__ Vw,
    const float* __restrict__ bcomb, const float* __restrict__ bout,
    float* __restrict__ out) {
  __shared__ __align__(16) unsigned short xs[32 * 264];  // 16.9 KB A tile
  __shared__ __align__(16) unsigned short BsEs[16640];   // 33.3 KB: Bs / Es alias
  __shared__ __align__(16) float vw_s[256];
  __shared__ float af_s[32];
  unsigned short* const Bs = BsEs;          // stage1 staging
  _Float16* const Es = (_Float16*)BsEs;     // 32 rows x 520 (512 + pad)

  const int tid = threadIdx.x;
  const int lane = tid & 63, wave = tid >> 6;
  const int quad = lane >> 4, l15 = lane & 15;
  const int rt0 = blockIdx.x * 32;          // global xf row base

  if (tid < 256) vw_s[tid] = -2.f * Vw[tid];

  // issue stage1 k0c=0 B loads (2048 x 16B segs, lane-linear into Bs)
#pragma unroll
  for (int i = 0; i < 4; ++i) {
    const int sb = wave * 256 + i * 64;
    const unsigned short* g = Wqb_t + (size_t)(sb + lane) * 8;
    __builtin_amdgcn_global_load_lds((gp1_t)g, (lp3_t)(Bs + sb * 8), 16, 0, 0);
  }

  // x tile: 32 rows x 256 fp32 -> bf16 -> xs (row stride 264: 2-way-free reads)
  {
    const int rl = tid >> 4, c0 = (tid & 15) * 16;
    const int r = rt0 + rl;
    const int b = r >> 13, l = (r >> 4) & 511, c = r & 15;
    const float* src = x + ((size_t)(b * 16 + c) * 512 + l) * 256 + c0;
    unsigned short* dst = xs + rl * 264 + c0;
#pragma unroll
    for (int j = 0; j < 2; ++j) {
      const float4 v0 = *(const float4*)(src + j * 8);
      const float4 v1 = *(const float4*)(src + j * 8 + 4);
      uint4 o;
      o.x = cvt_pk_bf16(v0.x, v0.y);
      o.y = cvt_pk_bf16(v0.z, v0.w);
      o.z = cvt_pk_bf16(v1.x, v1.y);
      o.w = cvt_pk_bf16(v1.z, v1.w);
      *(uint4*)(dst + j * 8) = o;
    }
  }
  __syncthreads();  // xs ready; k0c=0 B tile landed (barrier drains vmcnt)

  // ---------- stage 1: E[32 x 512] ----------
  f32x4 acc[2][4] = {};
  for (int k0c = 0; k0c < 8; ++k0c) {
    bf16x8 af[2], bfr[4];
#pragma unroll
    for (int mi = 0; mi < 2; ++mi)
      af[mi] = *(const bf16x8*)&xs[(mi * 16 + l15) * 264 + k0c * 32 + quad * 8];
#pragma unroll
    for (int ni = 0; ni < 4; ++ni)
      bfr[ni] = *(const bf16x8*)&Bs[(quad * 512 + wave * 64 + ni * 16 + l15) * 8];
    __syncthreads();  // frags in regs; Bs free for next tile
    if (k0c < 7) {
#pragma unroll
      for (int i = 0; i < 4; ++i) {
        const int sb = wave * 256 + i * 64;
        const unsigned short* g =
            Wqb_t + ((size_t)(k0c + 1) * 2048 + sb + lane) * 8;
        __builtin_amdgcn_global_load_lds((gp1_t)g, (lp3_t)(Bs + sb * 8), 16, 0, 0);
      }
    }
#pragma unroll
    for (int mi = 0; mi < 2; ++mi)
#pragma unroll
      for (int ni = 0; ni < 4; ++ni)
        acc[mi][ni] = __builtin_amdgcn_mfma_f32_16x16x32_bf16(
            bfr[ni], af[mi], acc[mi][ni], 0, 0, 0);
    __syncthreads();  // drains vmcnt: next tile ready
  }

  // stage-1 epilogue: E = exp2(clamp(acc*log2e + bsc, +-7.5)) -> Es (over Bs)
  // (half-exponent: E = e^z; same effective clamp as +-15 on 2z)
#pragma unroll
  for (int mi = 0; mi < 2; ++mi) {
    const int rl = mi * 16 + l15;
#pragma unroll
    for (int ni = 0; ni < 4; ++ni) {
      const int n = wave * 64 + ni * 16 + quad * 4;
      const float4 bs = *(const float4*)(bsc + n);
      const float SC2 = 1.4426950408889634f;  // log2(e)
      h16x4 st;
      st[0] = (_Float16)__builtin_amdgcn_exp2f(
          fminf(7.5f, fmaxf(-7.5f, fmaf(acc[mi][ni][0], SC2, bs.x))));
      st[1] = (_Float16)__builtin_amdgcn_exp2f(
          fminf(7.5f, fmaxf(-7.5f, fmaf(acc[mi][ni][1], SC2, bs.y))));
      st[2] = (_Float16)__builtin_amdgcn_exp2f(
          fminf(7.5f, fmaxf(-7.5f, fmaf(acc[mi][ni][2], SC2, bs.z))));
      st[3] = (_Float16)__builtin_amdgcn_exp2f(
          fminf(7.5f, fmaxf(-7.5f, fmaf(acc[mi][ni][3], SC2, bs.w))));
      *(h16x4*)&Es[rl * 520 + n] = st;
    }
  }
  __syncthreads();  // Es visible to all waves

  // ---------- fused: score (VALU) || stage 2 (MFMA + L2 B-fetch) ----------
  f32x4 acc2[2][2] = {};
  {
    const int p = tid >> 8, qc = (tid >> 4) & 15, kc = tid & 15;
    const _Float16* eqp = Es + (p * 16 + qc) * 520;
    const _Float16* ekp = Es + (p * 16 + kc) * 520 + 256;
    const unsigned short* wb2 = Wcb_t + (size_t)(quad * 256 + wave * 32 + l15) * 8;
    bf16x8 bcur0 = *(const bf16x8*)(wb2);
    bf16x8 bcur1 = *(const bf16x8*)(wb2 + 128);
    float asum = 0.f;
#pragma unroll
    for (int c = 0; c < 8; ++c) {
      bf16x8 bnxt0, bnxt1;
      if (c < 7) {  // prefetch next chunk's B-frags (covered by score VALU)
        bnxt0 = *(const bf16x8*)(wb2 + (size_t)(c + 1) * 8192);
        bnxt1 = *(const bf16x8*)(wb2 + (size_t)(c + 1) * 8192 + 128);
      }
      bf16x8 af0 = *(const bf16x8*)&xs[l15 * 264 + c * 32 + quad * 8];
      bf16x8 af1 = *(const bf16x8*)&xs[(16 + l15) * 264 + c * 32 + quad * 8];
      // 4 score iterations over d = 32c .. 32c+31 (4-way batched rcp)
#pragma unroll
      for (int j = 0; j < 4; ++j) {
        const int d = c * 32 + j * 8;
        const h16x8 eq = *(const h16x8*)(eqp + d);
        const h16x8 ek = *(const h16x8*)(ekp + d);
        const h16x8 pr = eq * ek;  // p = e^{zq+zk} <= 2^15: f16-safe, pk_mul
        const f32x4 wv0 = *(const f32x4*)(vw_s + d);
        const f32x4 wv1 = *(const f32x4*)(vw_s + d + 4);
        const float p0 = (float)pr[0], p1 = (float)pr[1];
        const float p2 = (float)pr[2], p3 = (float)pr[3];
        const float p4 = (float)pr[4], p5 = (float)pr[5];
        const float p6 = (float)pr[6], p7 = (float)pr[7];
        const float A0 = fmaf(p0, p0, 1.f), A1 = fmaf(p1, p1, 1.f);
        const float A2 = fmaf(p2, p2, 1.f), A3 = fmaf(p3, p3, 1.f);
        const float A4 = fmaf(p4, p4, 1.f), A5 = fmaf(p5, p5, 1.f);
        const float A6 = fmaf(p6, p6, 1.f), A7 = fmaf(p7, p7, 1.f);
        // group 0: sum wv0_i/A_i = num/(A0A1A2A3), one rcp
        {
          const float P01 = A0 * A1, P23 = A2 * A3;
          const float i1 = fmaf(wv0.y, A0, wv0.x * A1);
          const float i2 = fmaf(wv0.w, A2, wv0.z * A3);
          const float num = fmaf(i2, P01, i1 * P23);
          asum = fmaf(num, __builtin_amdgcn_rcpf(P01 * P23), asum);
        }
        // group 1
        {
          const float P45 = A4 * A5, P67 = A6 * A7;
          const float i1 = fmaf(wv1.y, A4, wv1.x * A5);
          const float i2 = fmaf(wv1.w, A6, wv1.z * A7);
          const float num = fmaf(i2, P45, i1 * P67);
          asum = fmaf(num, __builtin_amdgcn_rcpf(P45 * P67), asum);
        }
      }
      // 4 MFMAs for stage2 chunk c (separate pipe; overlaps score VALU)
      __builtin_amdgcn_s_setprio(1);
      acc2[0][0] = __builtin_amdgcn_mfma_f32_16x16x32_bf16(bcur0, af0, acc2[0][0], 0, 0, 0);
      acc2[0][1] = __builtin_amdgcn_mfma_f32_16x16x32_bf16(bcur1, af0, acc2[0][1], 0, 0, 0);
      acc2[1][0] = __builtin_amdgcn_mfma_f32_16x16x32_bf16(bcur0, af1, acc2[1][0], 0, 0, 0);
      acc2[1][1] = __builtin_amdgcn_mfma_f32_16x16x32_bf16(bcur1, af1, acc2[1][1], 0, 0, 0);
      __builtin_amdgcn_s_setprio(0);
      bcur0 = bnxt0; bcur1 = bnxt1;
    }
    // score reduction + diagonal softmax weight
    float s = asum;
    float m = s;
    for (int off = 8; off; off >>= 1) m = fmaxf(m, __shfl_xor(m, off, 16));
    const float e = __builtin_amdgcn_exp2f((s - m) * 1.4426950408889634f);
    float sum = e;
    for (int off = 8; off; off >>= 1) sum += __shfl_xor(sum, off, 16);
    if (kc == qc) af_s[p * 16 + qc] = e / sum;
  }
  __syncthreads();  // af_s visible to all waves

  // stage-2 epilogue: out = a*(acc2+bcomb)+bout, permuted (b,c,l,d) store
#pragma unroll
  for (int mi = 0; mi < 2; ++mi) {
    const int rl = mi * 16 + l15;
    const int r = rt0 + rl;
    const int c = r & 15, p = r >> 4;
    const int l = p & 511, b = p >> 9;
    const float av = af_s[rl];
    float* orow = out + ((size_t)(b * 16 + c) * 512 + l) * 256;
#pragma unroll
    for (int ni = 0; ni < 2; ++ni) {
      const int n = wave * 32 + ni * 16 + quad * 4;
      const float4 bc = *(const float4*)(bcomb + n);
      const float4 bo = *(const float4*)(bout + n);
      float4 o;
      o.x = fmaf(av, acc2[mi][ni][0] + bc.x, bo.x);
      o.y = fmaf(av, acc2[mi][ni][1] + bc.y, bo.y);
      o.z = fmaf(av, acc2[mi][ni][2] + bc.z, bo.z);
      o.w = fmaf(av, acc2[mi][ni][3] + bc.w, bo.w);
      *(float4*)(orow + n) = o;
    }
  }
}

extern "C" void kernel_launch(void* const* d_in, const int* in_sizes, int n_in,
                              void* d_out, int out_size, void* d_ws, size_t ws_size,
                              hipStream_t stream) {
  (void)in_sizes; (void)n_in; (void)out_size; (void)ws_size;
  const float* x    = (const float*)d_in[0];
  const float* Wqkv = (const float*)d_in[1];
  const float* bqkv = (const float*)d_in[2];
  const float* Vw   = (const float*)d_in[3];
  const float* bh   = (const float*)d_in[5];
  const float* Wout = (const float*)d_in[7];
  const float* bout = (const float*)d_in[8];
  float* out = (float*)d_out;

  // ws: bcomb f32 256 | bsc f32 512 | Wqb_t bf16 512*256 | Wcb_t bf16 256*256
  float* bcomb = (float*)d_ws;
  float* bsc = bcomb + 256;
  unsigned short* Wqb_t = (unsigned short*)(bsc + 512);
  unsigned short* Wcb_t = Wqb_t + (size_t)512 * 256;

  ca_prep_kernel<<<dim3(320), dim3(256), 0, stream>>>(
      Wqkv, Wout, bqkv, bh, Wqb_t, Wcb_t, bcomb, bsc);
  ca_fused<<<dim3(2048), dim3(512), 0, stream>>>(
      x, Wqb_t, Wcb_t, bsc, Vw, bcomb, bout, out);
}

// Round 7
// 191.040 us; speedup vs baseline: 1.6204x; 1.6204x over previous
//
#include <hip/hip_runtime.h>

// cAttention B=8, C=16, L=512, D=256 (fp32 in/out).
// R12 = R10 skeleton (best: 83us fused) + pressure-neutral score diet.
//   R11's batched-rcp SPILLED (WRITE_SIZE 65->408MB = scratch): 20 live f32
//   temporaries under the 85-VGPR cap of __launch_bounds__(512,6).
//   R12 keeps R10's per-element rcp (no new live scalars) and only swaps the
//   score FRONT-END to packed f16:
//     - Es stores HALF-exponent e^z = exp2(clamp(z*log2e, +-7.5))
//       (same effective clamp as R10's +-15 on 2z; validated in R8).
//     - score: pr = eq*ek (v_pk_mul_f16 x4), xm = pr*pr+1 (v_pk_fma_f16 x4),
//       sg = rcp((float)xm) per element. f16 inf/1 saturation of pr^2 gives
//       exactly the correct tanh saturation limits.
//   Everything else byte-identical to R10 (stage1, fused stage2, epilogues).

typedef __attribute__((ext_vector_type(8))) short bf16x8;
typedef __attribute__((ext_vector_type(4))) float f32x4;
typedef __attribute__((ext_vector_type(8))) _Float16 h16x8;
typedef __attribute__((ext_vector_type(4))) _Float16 h16x4;
typedef const __attribute__((address_space(1))) void* gp1_t;
typedef __attribute__((address_space(3))) void* lp3_t;

__device__ __forceinline__ unsigned short f2bf(float f) {
  union { float f; unsigned int u; } v; v.f = f;
  return (unsigned short)((v.u + 0x7FFFu + ((v.u >> 16) & 1u)) >> 16);
}

__device__ __forceinline__ unsigned int cvt_pk_bf16(float a, float b) {
  unsigned int r;
  asm("v_cvt_pk_bf16_f32 %0, %1, %2" : "=v"(r) : "v"(a), "v"(b));
  return r;  // lo = bf16(a), hi = bf16(b)
}

// ---- prep: Wqb_t = transpose-pack(Wqkv[0:512]) ; Wcb_t = pack(Wout @ Wv) ;
//      bcomb = Wout @ bv.  Layout: W_t[k>>3][n][8] (8 consecutive k per 16B). ----
__global__ __launch_bounds__(256) void ca_prep_kernel(
    const float* __restrict__ Wqkv, const float* __restrict__ Wout,
    const float* __restrict__ bqkv,
    unsigned short* __restrict__ Wqb_t, unsigned short* __restrict__ Wcb_t,
    float* __restrict__ bcomb) {
  const int blk = blockIdx.x;
  if (blk < 64) {
    // convert+transpose Wqkv (512x256 f32) -> Wqb_t[k8][512][8] bf16
    const int t = blk * 256 + threadIdx.x;  // 16384 threads
    const int k8 = t >> 9, n = t & 511;
    const float* src = Wqkv + (size_t)n * 256 + k8 * 8;
    const float4 v0 = *(const float4*)src;
    const float4 v1 = *(const float4*)(src + 4);
    bf16x8 o;
    o[0] = (short)f2bf(v0.x); o[1] = (short)f2bf(v0.y);
    o[2] = (short)f2bf(v0.z); o[3] = (short)f2bf(v0.w);
    o[4] = (short)f2bf(v1.x); o[5] = (short)f2bf(v1.y);
    o[6] = (short)f2bf(v1.z); o[7] = (short)f2bf(v1.w);
    *(bf16x8*)(Wqb_t + (size_t)t * 8) = o;  // t = k8*512 + n: coalesced store
    return;
  }
  const int dp = blk - 64;       // output row n (0..255)
  const int e = threadIdx.x;     // k (0..255)
  const float* wrow = Wout + (size_t)dp * 256;
  float acc = 0.f;
  for (int f = 0; f < 256; ++f)
    acc = fmaf(wrow[f], Wqkv[(size_t)(512 + f) * 256 + e], acc);
  Wcb_t[((size_t)(e >> 3) * 256 + dp) * 8 + (e & 7)] = f2bf(acc);
  if (e == 0) {
    float b = 0.f;
    for (int f = 0; f < 256; ++f) b = fmaf(wrow[f], bqkv[512 + f], b);
    bcomb[dp] = b;
  }
}

// ---- fused: qk MFMA + exp + (score || out MFMA) + softmax diag ----
__global__ __launch_bounds__(512, 6) void ca_fused(
    const float* __restrict__ x,               // (8,16,512,256) fp32
    const unsigned short* __restrict__ Wqb_t,  // [32][512][8] bf16
    const unsigned short* __restrict__ Wcb_t,  // [32][256][8] bf16
    const float* __restrict__ bqkv, const float* __restrict__ bh,
    const float* __restrict__ Vw,
    const float* __restrict__ bcomb, const float* __restrict__ bout,
    float* __restrict__ out) {
  __shared__ __align__(16) unsigned short xs[32 * 264];  // 16.9 KB A tile
  __shared__ __align__(16) unsigned short BsEs[16640];   // 33.3 KB: Bs / Es alias
  __shared__ __align__(16) float vw_s[256];
  __shared__ float af_s[32];
  unsigned short* const Bs = BsEs;          // stage1 staging
  _Float16* const Es = (_Float16*)BsEs;     // 32 rows x 520 (512 + pad)

  const int tid = threadIdx.x;
  const int lane = tid & 63, wave = tid >> 6;
  const int quad = lane >> 4, l15 = lane & 15;
  const int rt0 = blockIdx.x * 32;          // global xf row base

  if (tid < 256) vw_s[tid] = -2.f * Vw[tid];

  // issue stage1 k0c=0 B loads (2048 x 16B segs, lane-linear into Bs)
#pragma unroll
  for (int i = 0; i < 4; ++i) {
    const int sb = wave * 256 + i * 64;
    const unsigned short* g = Wqb_t + (size_t)(sb + lane) * 8;
    __builtin_amdgcn_global_load_lds((gp1_t)g, (lp3_t)(Bs + sb * 8), 16, 0, 0);
  }

  // x tile: 32 rows x 256 fp32 -> bf16 -> xs (row stride 264: 2-way-free reads)
  {
    const int rl = tid >> 4, c0 = (tid & 15) * 16;
    const int r = rt0 + rl;
    const int b = r >> 13, l = (r >> 4) & 511, c = r & 15;
    const float* src = x + ((size_t)(b * 16 + c) * 512 + l) * 256 + c0;
    unsigned short* dst = xs + rl * 264 + c0;
#pragma unroll
    for (int j = 0; j < 2; ++j) {
      const float4 v0 = *(const float4*)(src + j * 8);
      const float4 v1 = *(const float4*)(src + j * 8 + 4);
      uint4 o;
      o.x = cvt_pk_bf16(v0.x, v0.y);
      o.y = cvt_pk_bf16(v0.z, v0.w);
      o.z = cvt_pk_bf16(v1.x, v1.y);
      o.w = cvt_pk_bf16(v1.z, v1.w);
      *(uint4*)(dst + j * 8) = o;
    }
  }
  __syncthreads();  // xs ready; k0c=0 B tile landed (barrier drains vmcnt)

  // ---------- stage 1: E[32 x 512] ----------
  f32x4 acc[2][4] = {};
  for (int k0c = 0; k0c < 8; ++k0c) {
    bf16x8 af[2], bfr[4];
#pragma unroll
    for (int mi = 0; mi < 2; ++mi)
      af[mi] = *(const bf16x8*)&xs[(mi * 16 + l15) * 264 + k0c * 32 + quad * 8];
#pragma unroll
    for (int ni = 0; ni < 4; ++ni)
      bfr[ni] = *(const bf16x8*)&Bs[(quad * 512 + wave * 64 + ni * 16 + l15) * 8];
    __syncthreads();  // frags in regs; Bs free for next tile
    if (k0c < 7) {
#pragma unroll
      for (int i = 0; i < 4; ++i) {
        const int sb = wave * 256 + i * 64;
        const unsigned short* g =
            Wqb_t + ((size_t)(k0c + 1) * 2048 + sb + lane) * 8;
        __builtin_amdgcn_global_load_lds((gp1_t)g, (lp3_t)(Bs + sb * 8), 16, 0, 0);
      }
    }
#pragma unroll
    for (int mi = 0; mi < 2; ++mi)
#pragma unroll
      for (int ni = 0; ni < 4; ++ni)
        acc[mi][ni] = __builtin_amdgcn_mfma_f32_16x16x32_bf16(
            bfr[ni], af[mi], acc[mi][ni], 0, 0, 0);
    __syncthreads();  // drains vmcnt: next tile ready
  }

  // stage-1 epilogue: E = exp2(clamp((acc+bias)*log2e, +-7.5)) -> Es (over Bs)
  // half-exponent e^z; same effective clamp as R10's +-15 on 2z
  const float SC = 1.4426950408889634f;  // log2(e)
  const bool isq = (wave < 4);           // n < 256 -> q part (gets bh)
#pragma unroll
  for (int mi = 0; mi < 2; ++mi) {
    const int rl = mi * 16 + l15;
#pragma unroll
    for (int ni = 0; ni < 4; ++ni) {
      const int n = wave * 64 + ni * 16 + quad * 4;
      const float4 bq = *(const float4*)(bqkv + n);
      float4 bhv = make_float4(0.f, 0.f, 0.f, 0.f);
      if (isq) bhv = *(const float4*)(bh + n);
      h16x4 st;
      st[0] = (_Float16)__builtin_amdgcn_exp2f(
          fminf(7.5f, fmaxf(-7.5f, (acc[mi][ni][0] + bq.x + bhv.x) * SC)));
      st[1] = (_Float16)__builtin_amdgcn_exp2f(
          fminf(7.5f, fmaxf(-7.5f, (acc[mi][ni][1] + bq.y + bhv.y) * SC)));
      st[2] = (_Float16)__builtin_amdgcn_exp2f(
          fminf(7.5f, fmaxf(-7.5f, (acc[mi][ni][2] + bq.z + bhv.z) * SC)));
      st[3] = (_Float16)__builtin_amdgcn_exp2f(
          fminf(7.5f, fmaxf(-7.5f, (acc[mi][ni][3] + bq.w + bhv.w) * SC)));
      *(h16x4*)&Es[rl * 520 + n] = st;
    }
  }
  __syncthreads();  // Es visible to all waves

  // ---------- fused: score (VALU) || stage 2 (MFMA + L2 B-fetch) ----------
  f32x4 acc2[2][2] = {};
  {
    const int p = tid >> 8, qc = (tid >> 4) & 15, kc = tid & 15;
    const _Float16* eqp = Es + (p * 16 + qc) * 520;
    const _Float16* ekp = Es + (p * 16 + kc) * 520 + 256;
    const unsigned short* wb2 = Wcb_t + (size_t)(quad * 256 + wave * 32 + l15) * 8;
    bf16x8 bcur0 = *(const bf16x8*)(wb2);
    bf16x8 bcur1 = *(const bf16x8*)(wb2 + 128);
    const h16x8 one8 = {(_Float16)1.f, (_Float16)1.f, (_Float16)1.f,
                        (_Float16)1.f, (_Float16)1.f, (_Float16)1.f,
                        (_Float16)1.f, (_Float16)1.f};
    f32x4 a4 = {};
#pragma unroll
    for (int c = 0; c < 8; ++c) {
      bf16x8 bnxt0, bnxt1;
      if (c < 7) {  // prefetch next chunk's B-frags (covered by score VALU)
        bnxt0 = *(const bf16x8*)(wb2 + (size_t)(c + 1) * 8192);
        bnxt1 = *(const bf16x8*)(wb2 + (size_t)(c + 1) * 8192 + 128);
      }
      bf16x8 af0 = *(const bf16x8*)&xs[l15 * 264 + c * 32 + quad * 8];
      bf16x8 af1 = *(const bf16x8*)&xs[(16 + l15) * 264 + c * 32 + quad * 8];
      // 4 score iterations over d = 32c .. 32c+31 (packed-f16 front end)
#pragma unroll
      for (int j = 0; j < 4; ++j) {
        const int d = c * 32 + j * 8;
        const h16x8 eq = *(const h16x8*)(eqp + d);
        const h16x8 ek = *(const h16x8*)(ekp + d);
        const h16x8 pr = eq * ek;        // e^{zq+zk} <= 2^15: f16-safe
        const h16x8 xm = pr * pr + one8; // 1+e^{2z}; inf/1 saturation correct
        const f32x4 wv0 = *(const f32x4*)(vw_s + d);
        const f32x4 wv1 = *(const f32x4*)(vw_s + d + 4);
        f32x4 sg0, sg1;
        sg0.x = __builtin_amdgcn_rcpf((float)xm[0]);
        sg0.y = __builtin_amdgcn_rcpf((float)xm[1]);
        sg0.z = __builtin_amdgcn_rcpf((float)xm[2]);
        sg0.w = __builtin_amdgcn_rcpf((float)xm[3]);
        sg1.x = __builtin_amdgcn_rcpf((float)xm[4]);
        sg1.y = __builtin_amdgcn_rcpf((float)xm[5]);
        sg1.z = __builtin_amdgcn_rcpf((float)xm[6]);
        sg1.w = __builtin_amdgcn_rcpf((float)xm[7]);
        a4 += wv0 * sg0 + wv1 * sg1;
      }
      // 4 MFMAs for stage2 chunk c (separate pipe; overlaps score VALU)
      acc2[0][0] = __builtin_amdgcn_mfma_f32_16x16x32_bf16(bcur0, af0, acc2[0][0], 0, 0, 0);
      acc2[0][1] = __builtin_amdgcn_mfma_f32_16x16x32_bf16(bcur1, af0, acc2[0][1], 0, 0, 0);
      acc2[1][0] = __builtin_amdgcn_mfma_f32_16x16x32_bf16(bcur0, af1, acc2[1][0], 0, 0, 0);
      acc2[1][1] = __builtin_amdgcn_mfma_f32_16x16x32_bf16(bcur1, af1, acc2[1][1], 0, 0, 0);
      bcur0 = bnxt0; bcur1 = bnxt1;
    }
    // score reduction + diagonal softmax weight
    float s = (a4[0] + a4[1]) + (a4[2] + a4[3]);
    float m = s;
    for (int off = 8; off; off >>= 1) m = fmaxf(m, __shfl_xor(m, off, 16));
    const float e = __builtin_amdgcn_exp2f((s - m) * 1.4426950408889634f);
    float sum = e;
    for (int off = 8; off; off >>= 1) sum += __shfl_xor(sum, off, 16);
    if (kc == qc) af_s[p * 16 + qc] = e / sum;
  }
  __syncthreads();  // af_s visible to all waves

  // stage-2 epilogue: out = a*(acc2+bcomb)+bout, permuted (b,c,l,d) store
#pragma unroll
  for (int mi = 0; mi < 2; ++mi) {
    const int rl = mi * 16 + l15;
    const int r = rt0 + rl;
    const int c = r & 15, p = r >> 4;
    const int l = p & 511, b = p >> 9;
    const float av = af_s[rl];
    float* orow = out + ((size_t)(b * 16 + c) * 512 + l) * 256;
#pragma unroll
    for (int ni = 0; ni < 2; ++ni) {
      const int n = wave * 32 + ni * 16 + quad * 4;
      const float4 bc = *(const float4*)(bcomb + n);
      const float4 bo = *(const float4*)(bout + n);
      float4 o;
      o.x = fmaf(av, acc2[mi][ni][0] + bc.x, bo.x);
      o.y = fmaf(av, acc2[mi][ni][1] + bc.y, bo.y);
      o.z = fmaf(av, acc2[mi][ni][2] + bc.z, bo.z);
      o.w = fmaf(av, acc2[mi][ni][3] + bc.w, bo.w);
      *(float4*)(orow + n) = o;
    }
  }
}

extern "C" void kernel_launch(void* const* d_in, const int* in_sizes, int n_in,
                              void* d_out, int out_size, void* d_ws, size_t ws_size,
                              hipStream_t stream) {
  (void)in_sizes; (void)n_in; (void)out_size; (void)ws_size;
  const float* x    = (const float*)d_in[0];
  const float* Wqkv = (const float*)d_in[1];
  const float* bqkv = (const float*)d_in[2];
  const float* Vw   = (const float*)d_in[3];
  const float* bh   = (const float*)d_in[5];
  const float* Wout = (const float*)d_in[7];
  const float* bout = (const float*)d_in[8];
  float* out = (float*)d_out;

  // ws: bcomb fp32 256 | Wqb_t bf16 512*256 | Wcb_t bf16 256*256
  float* bcomb = (float*)d_ws;
  unsigned short* Wqb_t = (unsigned short*)(bcomb + 256);
  unsigned short* Wcb_t = Wqb_t + (size_t)512 * 256;

  ca_prep_kernel<<<dim3(320), dim3(256), 0, stream>>>(
      Wqkv, Wout, bqkv, Wqb_t, Wcb_t, bcomb);
  ca_fused<<<dim3(2048), dim3(512), 0, stream>>>(
      x, Wqb_t, Wcb_t, bqkv, bh, Vw, bcomb, bout, out);
}